// Round 7
// baseline (112.694 us; speedup 1.0000x reference)
//
#include <hip/hip_runtime.h>

#define T_SEQ 4096
#define NBATCH 4
#define CDIM 1024
#define NHEAD 64
#define SCALE (1.0f / 32.0f)
#define BT (NBATCH * T_SEQ)
#define NW 16            // waves per attn block (key-split factor)
#define WREG 8960        // per-wave LDS region bytes: o[32][68] f32 + m + l
#define PSTR 9           // P-tile row stride in u64: 8 data slots + 1 pad
                         // (R6 bug: stride 5 < 8 slots -> cross-row clobber -> L=0 -> NaN)

typedef __bf16 bf16x8 __attribute__((ext_vector_type(8)));
typedef float f32x4 __attribute__((ext_vector_type(4)));
typedef unsigned long long u64;

__device__ __forceinline__ unsigned short f2bf(float f) {
  union { float f; unsigned u; } x;
  x.f = f;
  unsigned r = x.u + 0x7FFFu + ((x.u >> 16) & 1u);
  return (unsigned short)(r >> 16);
}

__device__ __forceinline__ unsigned pack_bf16(float lo, float hi) {
  return (unsigned)f2bf(lo) | ((unsigned)f2bf(hi) << 16);
}

__device__ __forceinline__ f32x4 mfma16(bf16x8 a, bf16x8 b, f32x4 c) {
  return __builtin_amdgcn_mfma_f32_16x16x32_bf16(a, b, c, 0, 0, 0);
}

__device__ __forceinline__ bf16x8 ones8() {
  bf16x8 v;
  for (int j = 0; j < 8; ++j) v[j] = (__bf16)1.0f;
  return v;
}

// ---------------------------------------------------------------------------
// Kernel 1: Wt[c][k] = W*(k, c%64) * (c<64 ? SCALE : 1), bf16, c in [0,192)
// ---------------------------------------------------------------------------
__global__ void prep_w(const float* __restrict__ Wq, const float* __restrict__ Wk,
                       const float* __restrict__ Wv, unsigned short* __restrict__ Wt) {
  int c = blockIdx.x;
  const float* W = (c < 64) ? Wq : (c < 128) ? Wk : Wv;
  int cc = c & 63;
  float sc = (c < 64) ? SCALE : 1.0f;
  for (int k = threadIdx.x; k < CDIM; k += blockDim.x)
    Wt[c * CDIM + k] = f2bf(W[k * NHEAD + cc] * sc);
}

// ---------------------------------------------------------------------------
// Kernel 2: fused QKV projection, BK=128 with register prefetch.
// M-tile = 16 rows, 1024 blocks x 4 waves -> 4 blocks/CU = 4 waves/SIMD.
// Wave w computes cols [48w,48w+48) for the 16 rows.
// Writes q,k row-major [BT][64] bf16; v transposed [64][BT] bf16.
// ---------------------------------------------------------------------------
__global__ __launch_bounds__(256) void proj_qkv(
    const float* __restrict__ x, const unsigned short* __restrict__ Wt,
    unsigned short* __restrict__ qws, unsigned short* __restrict__ kws,
    unsigned short* __restrict__ vtws) {
  __shared__ unsigned short xlds[16][136];  // 128 bf16 + 8 pad
  const int tid = threadIdx.x;
  const int lane = tid & 63;
  const int w = tid >> 6;
  const int g = lane >> 4;
  const int c15 = lane & 15;
  const int rb = blockIdx.x * 16;

  f32x4 acc[3];
  for (int j = 0; j < 3; j++) acc[j] = (f32x4){0.f, 0.f, 0.f, 0.f};

  const int sr = tid >> 4;        // staging row 0..15
  const int scc = (tid & 15) * 8; // staging k-offset within 128-chunk
  const float* xrow = x + (size_t)(rb + sr) * CDIM + scc;

  float4 cur[2];
  cur[0] = *(const float4*)(xrow);
  cur[1] = *(const float4*)(xrow + 4);

  for (int k0 = 0; k0 < CDIM; k0 += 128) {
    unsigned short pk[8];
    pk[0] = f2bf(cur[0].x); pk[1] = f2bf(cur[0].y);
    pk[2] = f2bf(cur[0].z); pk[3] = f2bf(cur[0].w);
    pk[4] = f2bf(cur[1].x); pk[5] = f2bf(cur[1].y);
    pk[6] = f2bf(cur[1].z); pk[7] = f2bf(cur[1].w);
    *(bf16x8*)&xlds[sr][scc] = *(bf16x8*)pk;
    __syncthreads();
    if (k0 + 128 < CDIM) {
      cur[0] = *(const float4*)(xrow + k0 + 128);
      cur[1] = *(const float4*)(xrow + k0 + 132);
    }

    for (int kk = 0; kk < 4; kk++) {
      bf16x8 a = *(bf16x8*)&xlds[c15][kk * 32 + g * 8];
      for (int bn = 0; bn < 3; bn++) {
        int col = w * 48 + bn * 16 + c15;
        bf16x8 bfrag =
            *(const bf16x8*)&Wt[(size_t)col * CDIM + k0 + kk * 32 + g * 8];
        acc[bn] = mfma16(a, bfrag, acc[bn]);
      }
    }
    __syncthreads();
  }

  for (int bn = 0; bn < 3; bn++) {
    int col = w * 48 + bn * 16 + c15;
    for (int r = 0; r < 4; r++) {
      unsigned short v = f2bf(acc[bn][r]);
      int t = rb + 4 * g + r;
      if (col < 64)
        qws[(size_t)t * 64 + col] = v;
      else if (col < 128)
        kws[(size_t)t * 64 + (col - 64)] = v;
      else
        vtws[(size_t)(col - 128) * BT + t] = v;
    }
  }
}

// ---------------------------------------------------------------------------
// Kernel 3: causal flash attention, swapped-operand + paired q-tiles.
// 256 blocks (4 batch x 64 pairs) x 16 waves (1024 thr, 4 waves/SIMD).
// Block does qt=pi then 127-pi (uniform 129 steps); wave w takes st=w,w+16,...
// S = mfma(K,Q): lane c holds q-row c, keys on 4g+r. Softmax state on the
// c-axis; l via ones-MFMA; defer-max THR=8. P tile per-wave in LDS, u64-only
// access, row stride PSTR=9 u64 (72 B = 8 data slots + 1 pad, NO overlap):
// read bank = (18c+4g)%32, 18c bijective over even residues -> uniform
// 4 lanes/bank-pair = wave64 b64 optimal (R5's stride 10 was 8-way).
// Per-wave LDS WREG=8960 B: P [32 rows][9 u64] (2304 B) during loop;
// partials o[32][68] f32 @0 (pad 68 kills 16-way epilogue conflict),
// m[32] @8704, l[32] @8832 after loop.
// ---------------------------------------------------------------------------
__global__ __launch_bounds__(1024, 4) void attn_fwd(
    const unsigned short* __restrict__ qws, const unsigned short* __restrict__ kws,
    const unsigned short* __restrict__ vtws, float* __restrict__ out) {
  __shared__ __align__(16) char smem[NW * WREG];  // 140 KiB
  const int tid = threadIdx.x;
  const int lane = tid & 63;
  const int w = tid >> 6;
  const int g = lane >> 4;
  const int c = lane & 15;
  const int b = blockIdx.x >> 6;
  const int pi = blockIdx.x & 63;
  const size_t rowbase = (size_t)b * T_SEQ;
  char* wbase = smem + w * WREG;
  u64* pl = (u64*)wbase;  // P tile: row stride PSTR u64
  const bf16x8 vone = ones8();

  for (int half = 0; half < 2; ++half) {
    const int qt = half ? (127 - pi) : pi;
    const int qb = qt * 32;
    const int nsteps = qt + 1;

    bf16x8 qf[2][2];
    for (int mi = 0; mi < 2; mi++)
      for (int hc = 0; hc < 2; hc++)
        qf[mi][hc] = *(const bf16x8*)&qws[(rowbase + qb + mi * 16 + c) * 64 +
                                          hc * 32 + g * 8];

    f32x4 o[2][4];
    f32x4 o5[2];
    float mrow[2];
    for (int mi = 0; mi < 2; mi++) {
      for (int nt = 0; nt < 4; nt++) o[mi][nt] = (f32x4){0.f, 0.f, 0.f, 0.f};
      o5[mi] = (f32x4){0.f, 0.f, 0.f, 0.f};
      mrow[mi] = -1e30f;
    }

    for (int st = w; st < nsteps; st += NW) {
      const int kt = st * 32;
      bf16x8 kc0[2], kc1[2], vc[4];
      for (int kn = 0; kn < 2; kn++) {
        kc0[kn] = *(const bf16x8*)&kws[(rowbase + kt + kn * 16 + c) * 64 + g * 8];
        kc1[kn] =
            *(const bf16x8*)&kws[(rowbase + kt + kn * 16 + c) * 64 + 32 + g * 8];
      }
      for (int nt = 0; nt < 4; nt++)
        vc[nt] =
            *(const bf16x8*)&vtws[(size_t)(nt * 16 + c) * BT + rowbase + kt + g * 8];

      // S = mfma(K, Q): lane c = q-row, reg r = key 4g+r (+16 kn)
      f32x4 sv[2][2];
      for (int mi = 0; mi < 2; mi++)
        for (int kn = 0; kn < 2; kn++) {
          f32x4 z = (f32x4){0.f, 0.f, 0.f, 0.f};
          z = mfma16(kc0[kn], qf[mi][0], z);
          sv[mi][kn] = mfma16(kc1[kn], qf[mi][1], z);
        }

      if (st == nsteps - 1) {  // diagonal tile: causal mask
        for (int mi = 0; mi < 2; mi++)
          for (int kn = 0; kn < 2; kn++)
            for (int r = 0; r < 4; r++) {
              int key = kt + kn * 16 + 4 * g + r;
              int qr = qb + mi * 16 + c;
              if (key > qr) sv[mi][kn][r] = -1e30f;
            }
      }

      for (int mi = 0; mi < 2; mi++) {
        float t = fmaxf(
            fmaxf(fmaxf(sv[mi][0][0], sv[mi][0][1]),
                  fmaxf(sv[mi][0][2], sv[mi][0][3])),
            fmaxf(fmaxf(sv[mi][1][0], sv[mi][1][1]),
                  fmaxf(sv[mi][1][2], sv[mi][1][3])));
        t = fmaxf(t, __shfl_xor(t, 16));
        t = fmaxf(t, __shfl_xor(t, 32));
        if (__any(t > mrow[mi] + 8.0f)) {  // defer-max: rescale only on growth
          float mn = fmaxf(mrow[mi], t);
          float a = __expf(mrow[mi] - mn);
          mrow[mi] = mn;
          for (int nt = 0; nt < 4; nt++) o[mi][nt] *= a;
          o5[mi] *= a;
        }
        for (int kn = 0; kn < 2; kn++)
          for (int r = 0; r < 4; r++)
            sv[mi][kn][r] = __expf(sv[mi][kn][r] - mrow[mi]);
        unsigned d0 = pack_bf16(sv[mi][0][0], sv[mi][0][1]);
        unsigned d1 = pack_bf16(sv[mi][0][2], sv[mi][0][3]);
        unsigned d2 = pack_bf16(sv[mi][1][0], sv[mi][1][1]);
        unsigned d3 = pack_bf16(sv[mi][1][2], sv[mi][1][3]);
        int row = mi * 16 + c;
        pl[row * PSTR + g] = ((u64)d1 << 32) | d0;      // slots 0..3: keys 4g..4g+3
        pl[row * PSTR + 4 + g] = ((u64)d3 << 32) | d2;  // slots 4..7: keys 16+4g..
      }

      asm volatile("" ::: "memory");  // pin P stores before PV loads

      // PV: O = mfma(V, P); l = mfma(1, P). Lane c = q-row for both.
      for (int mi = 0; mi < 2; mi++) {
        union { u64 q[2]; bf16x8 v; } pu;
        pu.q[0] = pl[(mi * 16 + c) * PSTR + 2 * g];      // keys 8g..8g+3
        pu.q[1] = pl[(mi * 16 + c) * PSTR + 2 * g + 1];  // keys 8g+4..8g+7
        bf16x8 pa = pu.v;
        for (int nt = 0; nt < 4; nt++)
          o[mi][nt] = mfma16(vc[nt], pa, o[mi][nt]);
        o5[mi] = mfma16(vone, pa, o5[mi]);
      }
    }

    // ---- per-wave partials (P region dead now); o stride 68 f32 ----
    float* ow = (float*)wbase;
    float* mw = (float*)(wbase + 8704);
    float* lw = (float*)(wbase + 8832);
    for (int mi = 0; mi < 2; mi++)
      for (int nt = 0; nt < 4; nt++)
        for (int r = 0; r < 4; r++)
          ow[(mi * 16 + c) * 68 + nt * 16 + 4 * g + r] = o[mi][nt][r];
    if (g == 0)
      for (int mi = 0; mi < 2; mi++) {
        mw[mi * 16 + c] = mrow[mi];
        lw[mi * 16 + c] = o5[mi][0];
      }
    __syncthreads();

    // ---- LSE-merge across 16 waves: 1024 thr x 2 = 32x64 outputs ----
    for (int i = 0; i < 2; i++) {
      int e = tid + i * 1024;
      int row = e >> 6;
      int d = e & 63;
      float M = -1e30f;
      for (int ww = 0; ww < NW; ww++)
        M = fmaxf(M, ((const float*)(smem + ww * WREG + 8704))[row]);
      float L = 0.f, O = 0.f;
      for (int ww = 0; ww < NW; ww++) {
        float mv = ((const float*)(smem + ww * WREG + 8704))[row];
        float f = __expf(mv - M);
        L += f * ((const float*)(smem + ww * WREG + 8832))[row];
        O += f * ((const float*)(smem + ww * WREG))[row * 68 + d];
      }
      out[(rowbase + qb + row) * 64 + d] = O / L;
    }
    __syncthreads();  // merge reads done before next half reuses P region
  }
}

// ---------------------------------------------------------------------------
extern "C" void kernel_launch(void* const* d_in, const int* in_sizes, int n_in,
                              void* d_out, int out_size, void* d_ws, size_t ws_size,
                              hipStream_t stream) {
  const float* x = (const float*)d_in[0];
  const float* Wq = (const float*)d_in[1];
  const float* Wk = (const float*)d_in[2];
  const float* Wv = (const float*)d_in[3];
  float* out = (float*)d_out;

  char* ws = (char*)d_ws;
  unsigned short* Wt = (unsigned short*)(ws);                          // 384 KB
  unsigned short* qws = (unsigned short*)(ws + 393216);                // 2 MB
  unsigned short* kws = (unsigned short*)(ws + 393216 + 2097152);      // 2 MB
  unsigned short* vtws = (unsigned short*)(ws + 393216 + 2 * 2097152); // 2 MB

  prep_w<<<dim3(192), dim3(256), 0, stream>>>(Wq, Wk, Wv, Wt);
  proj_qkv<<<dim3(1024), dim3(256), 0, stream>>>(x, Wt, qws, kws, vtws);
  attn_fwd<<<dim3(256), dim3(1024), 0, stream>>>(qws, kws, vtws, out);
}

// Round 8
// 84.090 us; speedup vs baseline: 1.3402x; 1.3402x over previous
//
#include <hip/hip_runtime.h>

#define T_SEQ 4096
#define NBATCH 4
#define CDIM 1024
#define NHEAD 64
#define SCALE (1.0f / 32.0f)
#define BT (NBATCH * T_SEQ)
#define NW 12            // waves per attn block (key-split factor)
#define WREG 8960        // per-wave LDS region bytes: o[32][68] f32 + m + l
#define PSTR 9           // P-tile row stride in u64: 8 data slots + 1 pad

typedef __bf16 bf16x8 __attribute__((ext_vector_type(8)));
typedef float f32x4 __attribute__((ext_vector_type(4)));
typedef unsigned long long u64;

__device__ __forceinline__ unsigned short f2bf(float f) {
  union { float f; unsigned u; } x;
  x.f = f;
  unsigned r = x.u + 0x7FFFu + ((x.u >> 16) & 1u);
  return (unsigned short)(r >> 16);
}

__device__ __forceinline__ unsigned pack_bf16(float lo, float hi) {
  return (unsigned)f2bf(lo) | ((unsigned)f2bf(hi) << 16);
}

__device__ __forceinline__ f32x4 mfma16(bf16x8 a, bf16x8 b, f32x4 c) {
  return __builtin_amdgcn_mfma_f32_16x16x32_bf16(a, b, c, 0, 0, 0);
}

__device__ __forceinline__ bf16x8 ones8() {
  bf16x8 v;
  for (int j = 0; j < 8; ++j) v[j] = (__bf16)1.0f;
  return v;
}

// ---------------------------------------------------------------------------
// Kernel 1: Wt[c][k] = W*(k, c%64) * (c<64 ? SCALE : 1), bf16, c in [0,192)
// ---------------------------------------------------------------------------
__global__ void prep_w(const float* __restrict__ Wq, const float* __restrict__ Wk,
                       const float* __restrict__ Wv, unsigned short* __restrict__ Wt) {
  int c = blockIdx.x;
  const float* W = (c < 64) ? Wq : (c < 128) ? Wk : Wv;
  int cc = c & 63;
  float sc = (c < 64) ? SCALE : 1.0f;
  for (int k = threadIdx.x; k < CDIM; k += blockDim.x)
    Wt[c * CDIM + k] = f2bf(W[k * NHEAD + cc] * sc);
}

// ---------------------------------------------------------------------------
// Kernel 2: fused QKV projection, BK=128 with register prefetch.
// M-tile = 32 rows, 512 blocks x 4 waves -> 2 blocks/CU (R7's M-tile 16 was
// slower: halved per-block MFMA work, no TLP gain). Wave w: cols [48w,48w+48).
// Writes q,k row-major [BT][64] bf16; v transposed [64][BT] bf16.
// ---------------------------------------------------------------------------
__global__ __launch_bounds__(256) void proj_qkv(
    const float* __restrict__ x, const unsigned short* __restrict__ Wt,
    unsigned short* __restrict__ qws, unsigned short* __restrict__ kws,
    unsigned short* __restrict__ vtws) {
  __shared__ unsigned short xlds[32][136];  // 128 bf16 + 8 pad
  const int tid = threadIdx.x;
  const int lane = tid & 63;
  const int w = tid >> 6;
  const int g = lane >> 4;
  const int c15 = lane & 15;
  const int rb = blockIdx.x * 32;

  f32x4 acc[2][3];
  for (int i = 0; i < 2; i++)
    for (int j = 0; j < 3; j++) acc[i][j] = (f32x4){0.f, 0.f, 0.f, 0.f};

  const int sr = tid >> 3;         // staging row 0..31
  const int scc = (tid & 7) * 16;  // staging col base (floats)
  const float* xrow = x + (size_t)(rb + sr) * CDIM + scc;

  float4 cur[4];
  for (int i = 0; i < 4; i++) cur[i] = *(const float4*)(xrow + i * 4);

  for (int k0 = 0; k0 < CDIM; k0 += 128) {
    unsigned short pk[16];
    for (int i = 0; i < 4; i++) {
      pk[i * 4 + 0] = f2bf(cur[i].x);
      pk[i * 4 + 1] = f2bf(cur[i].y);
      pk[i * 4 + 2] = f2bf(cur[i].z);
      pk[i * 4 + 3] = f2bf(cur[i].w);
    }
    *(bf16x8*)&xlds[sr][scc] = *(bf16x8*)&pk[0];
    *(bf16x8*)&xlds[sr][scc + 8] = *(bf16x8*)&pk[8];
    __syncthreads();
    if (k0 + 128 < CDIM)
      for (int i = 0; i < 4; i++)
        cur[i] = *(const float4*)(xrow + k0 + 128 + i * 4);

    for (int kk = 0; kk < 4; kk++) {
      bf16x8 a[2];
      for (int mt = 0; mt < 2; mt++)
        a[mt] = *(bf16x8*)&xlds[mt * 16 + c15][kk * 32 + g * 8];
      for (int bn = 0; bn < 3; bn++) {
        int col = w * 48 + bn * 16 + c15;
        bf16x8 bfrag =
            *(const bf16x8*)&Wt[(size_t)col * CDIM + k0 + kk * 32 + g * 8];
        for (int mt = 0; mt < 2; mt++)
          acc[mt][bn] = mfma16(a[mt], bfrag, acc[mt][bn]);
      }
    }
    __syncthreads();
  }

  for (int mt = 0; mt < 2; mt++)
    for (int bn = 0; bn < 3; bn++) {
      int col = w * 48 + bn * 16 + c15;
      int row0 = rb + mt * 16 + 4 * g;
      for (int r = 0; r < 4; r++) {
        unsigned short v = f2bf(acc[mt][bn][r]);
        int t = row0 + r;
        if (col < 64)
          qws[(size_t)t * 64 + col] = v;
        else if (col < 128)
          kws[(size_t)t * 64 + (col - 64)] = v;
        else
          vtws[(size_t)(col - 128) * BT + t] = v;
      }
    }
}

// ---------------------------------------------------------------------------
// Kernel 3: causal flash attention, swapped-operand + paired q-tiles.
// 256 blocks (4 batch x 64 pairs) x 12 waves (768 thr = 3 waves/SIMD).
// Block shape rationale: reg cap = 512-per-SIMD-slot / waves-per-SIMD.
// 1024-thr blocks (R7) force 4/SIMD -> 128-reg cap -> spilled (~150 live).
// 768-thr blocks: 3/SIMD -> cap 170, fits state, +50% TLP vs R5's 2/SIMD.
// Block does qt=pi then 127-pi (uniform 129 steps); wave w: st=w,w+12,...
// S = mfma(K,Q): lane c holds q-row c, keys on 4g+r. Softmax state on c-axis;
// l via ones-MFMA; defer-max THR=8. P tile per-wave in LDS, u64-only access,
// row stride PSTR=9 u64 (72 B = 8 data slots + 1 pad): uniform 4 lanes per
// bank-pair on both store and load = wave64 b64 floor (R7 measured 0 confl).
// Per-wave LDS WREG=8960 B: P [32][9] u64 during loop; partials o[32][68]
// f32 @0 (pad 68), m[32] @8704, l[32] @8832 after loop.
// ---------------------------------------------------------------------------
__global__ __launch_bounds__(768, 3) void attn_fwd(
    const unsigned short* __restrict__ qws, const unsigned short* __restrict__ kws,
    const unsigned short* __restrict__ vtws, float* __restrict__ out) {
  __shared__ __align__(16) char smem[NW * WREG];  // 105 KiB
  const int tid = threadIdx.x;
  const int lane = tid & 63;
  const int w = tid >> 6;
  const int g = lane >> 4;
  const int c = lane & 15;
  const int b = blockIdx.x >> 6;
  const int pi = blockIdx.x & 63;
  const size_t rowbase = (size_t)b * T_SEQ;
  char* wbase = smem + w * WREG;
  u64* pl = (u64*)wbase;  // P tile: row stride PSTR u64
  const bf16x8 vone = ones8();

  for (int half = 0; half < 2; ++half) {
    const int qt = half ? (127 - pi) : pi;
    const int qb = qt * 32;
    const int nsteps = qt + 1;

    bf16x8 qf[2][2];
    for (int mi = 0; mi < 2; mi++)
      for (int hc = 0; hc < 2; hc++)
        qf[mi][hc] = *(const bf16x8*)&qws[(rowbase + qb + mi * 16 + c) * 64 +
                                          hc * 32 + g * 8];

    f32x4 o[2][4];
    f32x4 o5[2];
    float mrow[2];
    for (int mi = 0; mi < 2; mi++) {
      for (int nt = 0; nt < 4; nt++) o[mi][nt] = (f32x4){0.f, 0.f, 0.f, 0.f};
      o5[mi] = (f32x4){0.f, 0.f, 0.f, 0.f};
      mrow[mi] = -1e30f;
    }

    for (int st = w; st < nsteps; st += NW) {
      const int kt = st * 32;
      bf16x8 kc0[2], kc1[2], vc[4];
      for (int kn = 0; kn < 2; kn++) {
        kc0[kn] = *(const bf16x8*)&kws[(rowbase + kt + kn * 16 + c) * 64 + g * 8];
        kc1[kn] =
            *(const bf16x8*)&kws[(rowbase + kt + kn * 16 + c) * 64 + 32 + g * 8];
      }
      for (int nt = 0; nt < 4; nt++)
        vc[nt] =
            *(const bf16x8*)&vtws[(size_t)(nt * 16 + c) * BT + rowbase + kt + g * 8];

      // S = mfma(K, Q): lane c = q-row, reg r = key 4g+r (+16 kn)
      f32x4 sv[2][2];
      for (int mi = 0; mi < 2; mi++)
        for (int kn = 0; kn < 2; kn++) {
          f32x4 z = (f32x4){0.f, 0.f, 0.f, 0.f};
          z = mfma16(kc0[kn], qf[mi][0], z);
          sv[mi][kn] = mfma16(kc1[kn], qf[mi][1], z);
        }

      if (st == nsteps - 1) {  // diagonal tile: causal mask
        for (int mi = 0; mi < 2; mi++)
          for (int kn = 0; kn < 2; kn++)
            for (int r = 0; r < 4; r++) {
              int key = kt + kn * 16 + 4 * g + r;
              int qr = qb + mi * 16 + c;
              if (key > qr) sv[mi][kn][r] = -1e30f;
            }
      }

      for (int mi = 0; mi < 2; mi++) {
        float t = fmaxf(
            fmaxf(fmaxf(sv[mi][0][0], sv[mi][0][1]),
                  fmaxf(sv[mi][0][2], sv[mi][0][3])),
            fmaxf(fmaxf(sv[mi][1][0], sv[mi][1][1]),
                  fmaxf(sv[mi][1][2], sv[mi][1][3])));
        t = fmaxf(t, __shfl_xor(t, 16));
        t = fmaxf(t, __shfl_xor(t, 32));
        if (__any(t > mrow[mi] + 8.0f)) {  // defer-max: rescale only on growth
          float mn = fmaxf(mrow[mi], t);
          float a = __expf(mrow[mi] - mn);
          mrow[mi] = mn;
          for (int nt = 0; nt < 4; nt++) o[mi][nt] *= a;
          o5[mi] *= a;
        }
        for (int kn = 0; kn < 2; kn++)
          for (int r = 0; r < 4; r++)
            sv[mi][kn][r] = __expf(sv[mi][kn][r] - mrow[mi]);
        unsigned d0 = pack_bf16(sv[mi][0][0], sv[mi][0][1]);
        unsigned d1 = pack_bf16(sv[mi][0][2], sv[mi][0][3]);
        unsigned d2 = pack_bf16(sv[mi][1][0], sv[mi][1][1]);
        unsigned d3 = pack_bf16(sv[mi][1][2], sv[mi][1][3]);
        int row = mi * 16 + c;
        pl[row * PSTR + g] = ((u64)d1 << 32) | d0;      // slots 0..3: keys 4g..4g+3
        pl[row * PSTR + 4 + g] = ((u64)d3 << 32) | d2;  // slots 4..7: keys 16+4g..
      }

      asm volatile("" ::: "memory");  // pin P stores before PV loads

      // PV: O = mfma(V, P); l = mfma(1, P). Lane c = q-row for both.
      for (int mi = 0; mi < 2; mi++) {
        union { u64 q[2]; bf16x8 v; } pu;
        pu.q[0] = pl[(mi * 16 + c) * PSTR + 2 * g];      // keys 8g..8g+3
        pu.q[1] = pl[(mi * 16 + c) * PSTR + 2 * g + 1];  // keys 8g+4..8g+7
        bf16x8 pa = pu.v;
        for (int nt = 0; nt < 4; nt++)
          o[mi][nt] = mfma16(vc[nt], pa, o[mi][nt]);
        o5[mi] = mfma16(vone, pa, o5[mi]);
      }
    }

    // ---- per-wave partials (P region dead now); o stride 68 f32 ----
    float* ow = (float*)wbase;
    float* mw = (float*)(wbase + 8704);
    float* lw = (float*)(wbase + 8832);
    for (int mi = 0; mi < 2; mi++)
      for (int nt = 0; nt < 4; nt++)
        for (int r = 0; r < 4; r++)
          ow[(mi * 16 + c) * 68 + nt * 16 + 4 * g + r] = o[mi][nt][r];
    if (g == 0)
      for (int mi = 0; mi < 2; mi++) {
        mw[mi * 16 + c] = mrow[mi];
        lw[mi * 16 + c] = o5[mi][0];
      }
    __syncthreads();

    // ---- LSE-merge across 12 waves: 768 thr x 3 (guarded) = 32x64 outputs ----
    for (int i = 0; i < 3; i++) {
      int e = tid + i * 768;
      if (e < 2048) {
        int row = e >> 6;
        int d = e & 63;
        float M = -1e30f;
        for (int ww = 0; ww < NW; ww++)
          M = fmaxf(M, ((const float*)(smem + ww * WREG + 8704))[row]);
        float L = 0.f, O = 0.f;
        for (int ww = 0; ww < NW; ww++) {
          float mv = ((const float*)(smem + ww * WREG + 8704))[row];
          float f = __expf(mv - M);
          L += f * ((const float*)(smem + ww * WREG + 8832))[row];
          O += f * ((const float*)(smem + ww * WREG))[row * 68 + d];
        }
        out[(rowbase + qb + row) * 64 + d] = O / L;
      }
    }
    __syncthreads();  // merge reads done before next half reuses P region
  }
}

// ---------------------------------------------------------------------------
extern "C" void kernel_launch(void* const* d_in, const int* in_sizes, int n_in,
                              void* d_out, int out_size, void* d_ws, size_t ws_size,
                              hipStream_t stream) {
  const float* x = (const float*)d_in[0];
  const float* Wq = (const float*)d_in[1];
  const float* Wk = (const float*)d_in[2];
  const float* Wv = (const float*)d_in[3];
  float* out = (float*)d_out;

  char* ws = (char*)d_ws;
  unsigned short* Wt = (unsigned short*)(ws);                          // 384 KB
  unsigned short* qws = (unsigned short*)(ws + 393216);                // 2 MB
  unsigned short* kws = (unsigned short*)(ws + 393216 + 2097152);      // 2 MB
  unsigned short* vtws = (unsigned short*)(ws + 393216 + 2 * 2097152); // 2 MB

  prep_w<<<dim3(192), dim3(256), 0, stream>>>(Wq, Wk, Wv, Wt);
  proj_qkv<<<dim3(512), dim3(256), 0, stream>>>(x, Wt, qws, kws, vtws);
  attn_fwd<<<dim3(256), dim3(768), 0, stream>>>(qws, kws, vtws, out);
}

// Round 9
// 81.060 us; speedup vs baseline: 1.3903x; 1.0374x over previous
//
#include <hip/hip_runtime.h>

#define T_SEQ 4096
#define NBATCH 4
#define CDIM 1024
#define NHEAD 64
#define SCALE (1.0f / 32.0f)
#define BT (NBATCH * T_SEQ)
#define NW 8             // waves per attn block (key-split factor)
#define WREG 8960        // per-wave LDS region bytes: o[32][68] f32 + m + l
#define PSTR 9           // P-tile row stride in u64: 8 data slots + 1 pad

typedef __bf16 bf16x8 __attribute__((ext_vector_type(8)));
typedef float f32x4 __attribute__((ext_vector_type(4)));
typedef unsigned long long u64;

__device__ __forceinline__ unsigned short f2bf(float f) {
  union { float f; unsigned u; } x;
  x.f = f;
  unsigned r = x.u + 0x7FFFu + ((x.u >> 16) & 1u);
  return (unsigned short)(r >> 16);
}

__device__ __forceinline__ unsigned pack_bf16(float lo, float hi) {
  return (unsigned)f2bf(lo) | ((unsigned)f2bf(hi) << 16);
}

__device__ __forceinline__ f32x4 mfma16(bf16x8 a, bf16x8 b, f32x4 c) {
  return __builtin_amdgcn_mfma_f32_16x16x32_bf16(a, b, c, 0, 0, 0);
}

__device__ __forceinline__ bf16x8 ones8() {
  bf16x8 v;
  for (int j = 0; j < 8; ++j) v[j] = (__bf16)1.0f;
  return v;
}

// ---------------------------------------------------------------------------
// Kernel 1: Wt[c][k] = W*(k, c%64) * (c<64 ? SCALE : 1), bf16, c in [0,192)
// ---------------------------------------------------------------------------
__global__ void prep_w(const float* __restrict__ Wq, const float* __restrict__ Wk,
                       const float* __restrict__ Wv, unsigned short* __restrict__ Wt) {
  int c = blockIdx.x;
  const float* W = (c < 64) ? Wq : (c < 128) ? Wk : Wv;
  int cc = c & 63;
  float sc = (c < 64) ? SCALE : 1.0f;
  for (int k = threadIdx.x; k < CDIM; k += blockDim.x)
    Wt[c * CDIM + k] = f2bf(W[k * NHEAD + cc] * sc);
}

// ---------------------------------------------------------------------------
// Kernel 2: fused QKV projection, BK=128 with register prefetch.
// M-tile = 32 rows, 512 blocks x 4 waves -> 2 blocks/CU.
// Writes q,k row-major [BT][64] bf16; v transposed [64][BT] bf16.
// ---------------------------------------------------------------------------
__global__ __launch_bounds__(256) void proj_qkv(
    const float* __restrict__ x, const unsigned short* __restrict__ Wt,
    unsigned short* __restrict__ qws, unsigned short* __restrict__ kws,
    unsigned short* __restrict__ vtws) {
  __shared__ unsigned short xlds[32][136];  // 128 bf16 + 8 pad
  const int tid = threadIdx.x;
  const int lane = tid & 63;
  const int w = tid >> 6;
  const int g = lane >> 4;
  const int c15 = lane & 15;
  const int rb = blockIdx.x * 32;

  f32x4 acc[2][3];
  for (int i = 0; i < 2; i++)
    for (int j = 0; j < 3; j++) acc[i][j] = (f32x4){0.f, 0.f, 0.f, 0.f};

  const int sr = tid >> 3;         // staging row 0..31
  const int scc = (tid & 7) * 16;  // staging col base (floats)
  const float* xrow = x + (size_t)(rb + sr) * CDIM + scc;

  float4 cur[4];
  for (int i = 0; i < 4; i++) cur[i] = *(const float4*)(xrow + i * 4);

  for (int k0 = 0; k0 < CDIM; k0 += 128) {
    unsigned short pk[16];
    for (int i = 0; i < 4; i++) {
      pk[i * 4 + 0] = f2bf(cur[i].x);
      pk[i * 4 + 1] = f2bf(cur[i].y);
      pk[i * 4 + 2] = f2bf(cur[i].z);
      pk[i * 4 + 3] = f2bf(cur[i].w);
    }
    *(bf16x8*)&xlds[sr][scc] = *(bf16x8*)&pk[0];
    *(bf16x8*)&xlds[sr][scc + 8] = *(bf16x8*)&pk[8];
    __syncthreads();
    if (k0 + 128 < CDIM)
      for (int i = 0; i < 4; i++)
        cur[i] = *(const float4*)(xrow + k0 + 128 + i * 4);

    for (int kk = 0; kk < 4; kk++) {
      bf16x8 a[2];
      for (int mt = 0; mt < 2; mt++)
        a[mt] = *(bf16x8*)&xlds[mt * 16 + c15][kk * 32 + g * 8];
      for (int bn = 0; bn < 3; bn++) {
        int col = w * 48 + bn * 16 + c15;
        bf16x8 bfrag =
            *(const bf16x8*)&Wt[(size_t)col * CDIM + k0 + kk * 32 + g * 8];
        for (int mt = 0; mt < 2; mt++)
          acc[mt][bn] = mfma16(a[mt], bfrag, acc[mt][bn]);
      }
    }
    __syncthreads();
  }

  for (int mt = 0; mt < 2; mt++)
    for (int bn = 0; bn < 3; bn++) {
      int col = w * 48 + bn * 16 + c15;
      int row0 = rb + mt * 16 + 4 * g;
      for (int r = 0; r < 4; r++) {
        unsigned short v = f2bf(acc[mt][bn][r]);
        int t = row0 + r;
        if (col < 64)
          qws[(size_t)t * 64 + col] = v;
        else if (col < 128)
          kws[(size_t)t * 64 + (col - 64)] = v;
        else
          vtws[(size_t)(col - 128) * BT + t] = v;
      }
    }
}

// ---------------------------------------------------------------------------
// Kernel 3: causal flash attention, swapped-operand + paired q-tiles +
// double-buffered K/V register prefetch.
// 256 blocks (4 batch x 64 pairs) x 8 waves (512 thr). Block does qt=pi then
// 127-pi (uniform 129 steps); wave w: st=w,w+8,...
// Chain analysis (R8): ~60% all-stall cycles came from K/V L2 latency
// exposed at step top (prefetch removed in R3 for spill reasons). Restored
// here: next step's K/V loads issue at iteration top, in flight under
// QK+softmax+P+PV (~400cy). __launch_bounds__(512,2) -> 256-reg cap, ~150
// demand, no spill (R2's failure was the (512,4) 128-reg cap).
// S = mfma(K,Q): lane c holds q-row c, keys on 4g+r. Softmax state on c-axis;
// l via ones-MFMA; defer-max THR=8. P tile per-wave LDS, u64-only, PSTR=9
// (72 B row: 8 slots + pad) = 0 bank conflicts (R8 measured). Per-wave WREG
// 8960 B: P [32][9] u64 in loop; o[32][68] f32 @0, m @8704, l @8832 after.
// ---------------------------------------------------------------------------
__global__ __launch_bounds__(512, 2) void attn_fwd(
    const unsigned short* __restrict__ qws, const unsigned short* __restrict__ kws,
    const unsigned short* __restrict__ vtws, float* __restrict__ out) {
  __shared__ __align__(16) char smem[NW * WREG];  // 70 KiB
  const int tid = threadIdx.x;
  const int lane = tid & 63;
  const int w = tid >> 6;
  const int g = lane >> 4;
  const int c = lane & 15;
  const int b = blockIdx.x >> 6;
  const int pi = blockIdx.x & 63;
  const size_t rowbase = (size_t)b * T_SEQ;
  char* wbase = smem + w * WREG;
  u64* pl = (u64*)wbase;  // P tile: row stride PSTR u64
  const bf16x8 vone = ones8();

  for (int half = 0; half < 2; ++half) {
    const int qt = half ? (127 - pi) : pi;
    const int qb = qt * 32;
    const int nsteps = qt + 1;

    bf16x8 qf[2][2];
    for (int mi = 0; mi < 2; mi++)
      for (int hc = 0; hc < 2; hc++)
        qf[mi][hc] = *(const bf16x8*)&qws[(rowbase + qb + mi * 16 + c) * 64 +
                                          hc * 32 + g * 8];

    f32x4 o[2][4];
    f32x4 o5[2];
    float mrow[2];
    for (int mi = 0; mi < 2; mi++) {
      for (int nt = 0; nt < 4; nt++) o[mi][nt] = (f32x4){0.f, 0.f, 0.f, 0.f};
      o5[mi] = (f32x4){0.f, 0.f, 0.f, 0.f};
      mrow[mi] = -1e30f;
    }

    // prologue: load K/V for this wave's first step
    bf16x8 kc0[2], kc1[2], vc[4];
    if (w < nsteps) {
      const int kt = w * 32;
      for (int kn = 0; kn < 2; kn++) {
        kc0[kn] = *(const bf16x8*)&kws[(rowbase + kt + kn * 16 + c) * 64 + g * 8];
        kc1[kn] =
            *(const bf16x8*)&kws[(rowbase + kt + kn * 16 + c) * 64 + 32 + g * 8];
      }
      for (int nt = 0; nt < 4; nt++)
        vc[nt] = *(const bf16x8*)&vtws[(size_t)(nt * 16 + c) * BT + rowbase + kt +
                                       g * 8];
    }

    for (int st = w; st < nsteps; st += NW) {
      const int kt = st * 32;
      const int stn = st + NW;
      // prefetch next step's K/V: in flight under QK + softmax + P + PV
      bf16x8 kn0[2], kn1[2], vn[4];
      if (stn < nsteps) {
        const int ktn = stn * 32;
        for (int kn = 0; kn < 2; kn++) {
          kn0[kn] =
              *(const bf16x8*)&kws[(rowbase + ktn + kn * 16 + c) * 64 + g * 8];
          kn1[kn] = *(const bf16x8*)&kws[(rowbase + ktn + kn * 16 + c) * 64 + 32 +
                                         g * 8];
        }
        for (int nt = 0; nt < 4; nt++)
          vn[nt] = *(const bf16x8*)&vtws[(size_t)(nt * 16 + c) * BT + rowbase +
                                         ktn + g * 8];
      }

      // S = mfma(K, Q): lane c = q-row, reg r = key 4g+r (+16 kn)
      f32x4 sv[2][2];
      for (int mi = 0; mi < 2; mi++)
        for (int kn = 0; kn < 2; kn++) {
          f32x4 z = (f32x4){0.f, 0.f, 0.f, 0.f};
          z = mfma16(kc0[kn], qf[mi][0], z);
          sv[mi][kn] = mfma16(kc1[kn], qf[mi][1], z);
        }

      if (st == nsteps - 1) {  // diagonal tile: causal mask
        for (int mi = 0; mi < 2; mi++)
          for (int kn = 0; kn < 2; kn++)
            for (int r = 0; r < 4; r++) {
              int key = kt + kn * 16 + 4 * g + r;
              int qr = qb + mi * 16 + c;
              if (key > qr) sv[mi][kn][r] = -1e30f;
            }
      }

      for (int mi = 0; mi < 2; mi++) {
        float t = fmaxf(
            fmaxf(fmaxf(sv[mi][0][0], sv[mi][0][1]),
                  fmaxf(sv[mi][0][2], sv[mi][0][3])),
            fmaxf(fmaxf(sv[mi][1][0], sv[mi][1][1]),
                  fmaxf(sv[mi][1][2], sv[mi][1][3])));
        t = fmaxf(t, __shfl_xor(t, 16));
        t = fmaxf(t, __shfl_xor(t, 32));
        if (__any(t > mrow[mi] + 8.0f)) {  // defer-max: rescale only on growth
          float mn = fmaxf(mrow[mi], t);
          float a = __expf(mrow[mi] - mn);
          mrow[mi] = mn;
          for (int nt = 0; nt < 4; nt++) o[mi][nt] *= a;
          o5[mi] *= a;
        }
        for (int kn = 0; kn < 2; kn++)
          for (int r = 0; r < 4; r++)
            sv[mi][kn][r] = __expf(sv[mi][kn][r] - mrow[mi]);
        unsigned d0 = pack_bf16(sv[mi][0][0], sv[mi][0][1]);
        unsigned d1 = pack_bf16(sv[mi][0][2], sv[mi][0][3]);
        unsigned d2 = pack_bf16(sv[mi][1][0], sv[mi][1][1]);
        unsigned d3 = pack_bf16(sv[mi][1][2], sv[mi][1][3]);
        int row = mi * 16 + c;
        pl[row * PSTR + g] = ((u64)d1 << 32) | d0;      // slots 0..3: keys 4g..4g+3
        pl[row * PSTR + 4 + g] = ((u64)d3 << 32) | d2;  // slots 4..7: keys 16+4g..
      }

      asm volatile("" ::: "memory");  // pin P stores before PV loads

      // PV: O = mfma(V, P); l = mfma(1, P). Lane c = q-row for both.
      for (int mi = 0; mi < 2; mi++) {
        union { u64 q[2]; bf16x8 v; } pu;
        pu.q[0] = pl[(mi * 16 + c) * PSTR + 2 * g];      // keys 8g..8g+3
        pu.q[1] = pl[(mi * 16 + c) * PSTR + 2 * g + 1];  // keys 8g+4..8g+7
        bf16x8 pa = pu.v;
        for (int nt = 0; nt < 4; nt++)
          o[mi][nt] = mfma16(vc[nt], pa, o[mi][nt]);
        o5[mi] = mfma16(vone, pa, o5[mi]);
      }

      // rotate double buffer
      if (stn < nsteps) {
        for (int kn = 0; kn < 2; kn++) {
          kc0[kn] = kn0[kn];
          kc1[kn] = kn1[kn];
        }
        for (int nt = 0; nt < 4; nt++) vc[nt] = vn[nt];
      }
    }

    // ---- per-wave partials (P region dead now); o stride 68 f32 ----
    float* ow = (float*)wbase;
    float* mw = (float*)(wbase + 8704);
    float* lw = (float*)(wbase + 8832);
    for (int mi = 0; mi < 2; mi++)
      for (int nt = 0; nt < 4; nt++)
        for (int r = 0; r < 4; r++)
          ow[(mi * 16 + c) * 68 + nt * 16 + 4 * g + r] = o[mi][nt][r];
    if (g == 0)
      for (int mi = 0; mi < 2; mi++) {
        mw[mi * 16 + c] = mrow[mi];
        lw[mi * 16 + c] = o5[mi][0];
      }
    __syncthreads();

    // ---- LSE-merge across 8 waves: 512 thr x 4 = 32x64 outputs ----
    for (int i = 0; i < 4; i++) {
      int e = tid + i * 512;
      int row = e >> 6;
      int d = e & 63;
      float M = -1e30f;
      for (int ww = 0; ww < NW; ww++)
        M = fmaxf(M, ((const float*)(smem + ww * WREG + 8704))[row]);
      float L = 0.f, O = 0.f;
      for (int ww = 0; ww < NW; ww++) {
        float mv = ((const float*)(smem + ww * WREG + 8704))[row];
        float f = __expf(mv - M);
        L += f * ((const float*)(smem + ww * WREG + 8832))[row];
        O += f * ((const float*)(smem + ww * WREG))[row * 68 + d];
      }
      out[(rowbase + qb + row) * 64 + d] = O / L;
    }
    __syncthreads();  // merge reads done before next half reuses P region
  }
}

// ---------------------------------------------------------------------------
extern "C" void kernel_launch(void* const* d_in, const int* in_sizes, int n_in,
                              void* d_out, int out_size, void* d_ws, size_t ws_size,
                              hipStream_t stream) {
  const float* x = (const float*)d_in[0];
  const float* Wq = (const float*)d_in[1];
  const float* Wk = (const float*)d_in[2];
  const float* Wv = (const float*)d_in[3];
  float* out = (float*)d_out;

  char* ws = (char*)d_ws;
  unsigned short* Wt = (unsigned short*)(ws);                          // 384 KB
  unsigned short* qws = (unsigned short*)(ws + 393216);                // 2 MB
  unsigned short* kws = (unsigned short*)(ws + 393216 + 2097152);      // 2 MB
  unsigned short* vtws = (unsigned short*)(ws + 393216 + 2 * 2097152); // 2 MB

  prep_w<<<dim3(192), dim3(256), 0, stream>>>(Wq, Wk, Wv, Wt);
  proj_qkv<<<dim3(512), dim3(256), 0, stream>>>(x, Wt, qws, kws, vtws);
  attn_fwd<<<dim3(256), dim3(512), 0, stream>>>(qws, kws, vtws, out);
}